// Round 3
// baseline (455.558 us; speedup 1.0000x reference)
//
#include <hip/hip_runtime.h>

// B=32, N=1024, D=256. out = softmax((x Wq^T + bq)(x Wk^T + bk)^T) (x Wv^T + bv)
// fp16 MFMA everywhere, fp32 accumulate. R3: no LDS staging for W/K/V — MFMA
// B-fragments are 16B-contiguous in global layout and L1/L2-hot; attn kt-loop
// is barrier-free (P round-trip LDS is wave-private).
#define NN 1024
#define DD 256

typedef __attribute__((ext_vector_type(8))) _Float16 f16x8;  // 8 fp16 = 4 VGPRs
typedef __attribute__((ext_vector_type(4))) float f32x4;

union H8 { f16x8 v; _Float16 s[8]; };

// ---------------- kernel 1: weights fp32 -> fp16 (concat [Wq;Wk;Wv] as [768][256]) ---
__global__ void wconv_kernel(const float* __restrict__ Wq, const float* __restrict__ Wk,
                             const float* __restrict__ Wv, _Float16* __restrict__ whf) {
  int idx = blockIdx.x * 256 + threadIdx.x;      // < 768*256
  int e = idx >> 8, d = idx & 255;
  const float* W = (e < 256) ? Wq : (e < 512 ? Wk : Wv);
  whf[idx] = (_Float16)W[(e & 255) * 256 + d];
}

// ---------------- kernel 2: QKV projection -------------------------------------------
// grid 512 blocks, 256 thr. Block = 64 m-rows x all 768 e-cols; A (traj) in regs once,
// W fragments direct from global (384 KB total, L2-resident). Barriers only in epilogue.
__global__ __launch_bounds__(256, 4) void proj_kernel(
    const float* __restrict__ traj,
    const float* __restrict__ bq, const float* __restrict__ bk, const float* __restrict__ bv,
    const _Float16* __restrict__ whf,
    _Float16* __restrict__ qhf, _Float16* __restrict__ khf,
    _Float16* __restrict__ vthf)
{
  __shared__ _Float16 Cs[64 * 88];    // 11264 B epilogue staging

  const int t = threadIdx.x;
  const int lane = t & 63, wave = t >> 6;
  const int col16 = lane & 15, quad = lane >> 4;
  const int mbase = blockIdx.x * 64;

  // A fragments straight from global fp32 (A[m=lane&15][k=quad*8+j]), row read once.
  f16x8 aq[8];
  {
    const float* ap = traj + (size_t)(mbase + wave * 16 + col16) * DD;
    for (int kk = 0; kk < 8; ++kk) {
      float4 u0 = *(const float4*)(ap + kk * 32 + quad * 8);
      float4 u1 = *(const float4*)(ap + kk * 32 + quad * 8 + 4);
      H8 xx;
      xx.s[0] = (_Float16)u0.x; xx.s[1] = (_Float16)u0.y;
      xx.s[2] = (_Float16)u0.z; xx.s[3] = (_Float16)u0.w;
      xx.s[4] = (_Float16)u1.x; xx.s[5] = (_Float16)u1.y;
      xx.s[6] = (_Float16)u1.z; xx.s[7] = (_Float16)u1.w;
      aq[kk] = xx.v;
    }
  }

  const f32x4 zero = {0.f, 0.f, 0.f, 0.f};

  for (int et = 0; et < 12; ++et) {
    f32x4 acc[4];
    acc[0] = zero; acc[1] = zero; acc[2] = zero; acc[3] = zero;
    const _Float16* wb = whf + (size_t)et * 64 * 256;   // 64 e-rows of this tile
    for (int kk = 0; kk < 8; ++kk)
      for (int nt = 0; nt < 4; ++nt) {
        f16x8 bw = *(const f16x8*)(wb + (nt * 16 + col16) * 256 + kk * 32 + quad * 8);
        acc[nt] = __builtin_amdgcn_mfma_f32_16x16x32_f16(aq[kk], bw, acc[nt], 0, 0, 0);
      }

    // epilogue for this 64-col tile: bias, fp16, coalesced store via LDS
    int ebase = et * 64;
    int sel = ebase >> 8;                    // 0=q 1=k 2=v
    const float* bias = (sel == 0) ? bq : (sel == 1 ? bk : bv);
    for (int nt = 0; nt < 4; ++nt) {
      float bvl = bias[(ebase & 255) + nt * 16 + col16];
      acc[nt][0] += bvl; acc[nt][1] += bvl; acc[nt][2] += bvl; acc[nt][3] += bvl;
    }
    __syncthreads();                         // prev iteration's Cs reads done
    if (sel < 2) {
      for (int nt = 0; nt < 4; ++nt)
        for (int r = 0; r < 4; ++r)          // C layout: col=lane&15, row=quad*4+r
          Cs[(wave * 16 + quad * 4 + r) * 88 + nt * 16 + col16] = (_Float16)acc[nt][r];
      __syncthreads();
      _Float16* dst = (sel == 0) ? qhf : khf;
      int row = t >> 2;
      int colg = ebase & 255;
      for (int i = 0; i < 2; ++i) {
        int c = (t & 3) + i * 4;             // 8 chunks of 16B per 64-col row
        *(int4*)(dst + (size_t)(mbase + row) * 256 + colg + c * 8) =
            *(const int4*)&Cs[row * 88 + c * 8];
      }
    } else {
      for (int nt = 0; nt < 4; ++nt)
        for (int r = 0; r < 4; ++r)          // transposed staging: [e_local][m_local]
          Cs[(nt * 16 + col16) * 88 + (wave * 16 + quad * 4 + r)] = (_Float16)acc[nt][r];
      __syncthreads();
      int trow = t >> 2;                     // e-local 0..63
      int dglob = (ebase - 512) + trow;
      int bb = mbase >> 10;
      int mloc = mbase & 1023;
      for (int i = 0; i < 2; ++i) {
        int c = (t & 3) + i * 4;
        *(int4*)(vthf + ((size_t)bb * 256 + dglob) * NN + mloc + c * 8) =
            *(const int4*)&Cs[trow * 88 + c * 8];
      }
    }
  }
}

// ---------------- kernel 3: flash attention ------------------------------------------
// grid (16,32): x = q-tile (64 rows), y = batch. 4 waves, wave owns 16 q-rows.
// K/V fragments direct from global (tile working sets L1/L2-hot); zero barriers.
__global__ __launch_bounds__(256, 3) void attn_kernel(
    const _Float16* __restrict__ qhf, const _Float16* __restrict__ khf,
    const _Float16* __restrict__ vthf, float* __restrict__ out)
{
  __shared__ _Float16 Ps[64 * 88];     // 11264 B, wave-private 16-row regions

  const int t = threadIdx.x;
  const int lane = t & 63, wave = t >> 6;
  const int col16 = lane & 15, quad = lane >> 4;
  const int qt = blockIdx.x, b = blockIdx.y;
  const int qrow0 = b * NN + qt * 64;

  // Q fragments direct from global fp16 (coalesced 64B/row)
  f16x8 aq[8];
  {
    const _Float16* qp = qhf + (size_t)(qrow0 + wave * 16 + col16) * DD;
    for (int kk = 0; kk < 8; ++kk)
      aq[kk] = *(const f16x8*)(qp + kk * 32 + quad * 8);
  }

  float m_i[4], l_i[4], alpha[4];
  f32x4 O[16];
  const f32x4 zero = {0.f, 0.f, 0.f, 0.f};
  for (int r = 0; r < 4; ++r) { m_i[r] = -3.0e38f; l_i[r] = 0.f; }
  for (int dt = 0; dt < 16; ++dt) O[dt] = zero;

  const _Float16* kbase = khf + (size_t)(b * NN) * DD;
  const _Float16* vbase = vthf + (size_t)b * DD * NN;

  for (int kt = 0; kt < 16; ++kt) {
    // S = Q K^T  (64 keys), K fragments direct from global
    f32x4 S[4]; S[0] = zero; S[1] = zero; S[2] = zero; S[3] = zero;
    const _Float16* kb = kbase + (size_t)(kt * 64) * DD;
    for (int kk = 0; kk < 8; ++kk)
      for (int nt = 0; nt < 4; ++nt) {
        f16x8 bk_ = *(const f16x8*)(kb + (nt * 16 + col16) * 256 + kk * 32 + quad * 8);
        S[nt] = __builtin_amdgcn_mfma_f32_16x16x32_f16(aq[kk], bk_, S[nt], 0, 0, 0);
      }

    // online softmax — rows quad*4+r are private to this wave's 16-lane quads
    for (int r = 0; r < 4; ++r) {
      float vmax = fmaxf(fmaxf(S[0][r], S[1][r]), fmaxf(S[2][r], S[3][r]));
      vmax = fmaxf(vmax, __shfl_xor(vmax, 1));
      vmax = fmaxf(vmax, __shfl_xor(vmax, 2));
      vmax = fmaxf(vmax, __shfl_xor(vmax, 4));
      vmax = fmaxf(vmax, __shfl_xor(vmax, 8));
      float nm = fmaxf(m_i[r], vmax);
      alpha[r] = __expf(m_i[r] - nm);
      float rs = 0.f;
      for (int nt = 0; nt < 4; ++nt) {
        float pv = __expf(S[nt][r] - nm);
        S[nt][r] = pv;
        rs += pv;
      }
      rs += __shfl_xor(rs, 1);
      rs += __shfl_xor(rs, 2);
      rs += __shfl_xor(rs, 4);
      rs += __shfl_xor(rs, 8);
      l_i[r] = l_i[r] * alpha[r] + rs;
      m_i[r] = nm;
    }
    for (int dt = 0; dt < 16; ++dt)
      for (int r = 0; r < 4; ++r) O[dt][r] *= alpha[r];

    // P -> LDS (C layout -> A layout round trip; rows are wave-private, no barrier)
    for (int nt = 0; nt < 4; ++nt)
      for (int r = 0; r < 4; ++r)
        Ps[(wave * 16 + quad * 4 + r) * 88 + nt * 16 + col16] = (_Float16)S[nt][r];
    f16x8 ap[2];
    for (int k2 = 0; k2 < 2; ++k2)
      ap[k2] = *(const f16x8*)&Ps[(wave * 16 + col16) * 88 + k2 * 32 + quad * 8];

    // O += P V, V fragments direct from global (VT layout: contiguous along keys)
    for (int dt = 0; dt < 16; ++dt)
      for (int k2 = 0; k2 < 2; ++k2) {
        f16x8 bv_ = *(const f16x8*)(vbase + (size_t)(dt * 16 + col16) * NN +
                                    kt * 64 + k2 * 32 + quad * 8);
        O[dt] = __builtin_amdgcn_mfma_f32_16x16x32_f16(ap[k2], bv_, O[dt], 0, 0, 0);
      }
  }

  // epilogue: O /= l, fp32 store (lanes 0..15 contiguous 64B per instr)
  for (int r = 0; r < 4; ++r) {
    float inv = 1.0f / l_i[r];
    float* orow = out + (size_t)(qrow0 + wave * 16 + quad * 4 + r) * DD;
    for (int dt = 0; dt < 16; ++dt)
      orow[dt * 16 + col16] = O[dt][r] * inv;
  }
}

// ---------------- launch -------------------------------------------------------------
extern "C" void kernel_launch(void* const* d_in, const int* in_sizes, int n_in,
                              void* d_out, int out_size, void* d_ws, size_t ws_size,
                              hipStream_t stream) {
  const float* traj = (const float*)d_in[0];
  const float* Wq   = (const float*)d_in[1];
  const float* bq   = (const float*)d_in[2];
  const float* Wk   = (const float*)d_in[3];
  const float* bk   = (const float*)d_in[4];
  const float* Wv   = (const float*)d_in[5];
  const float* bv   = (const float*)d_in[6];

  // workspace layout (fp16): q[32768][256] | k[32768][256] | vT[32][256][1024] | w[768][256]
  _Float16* qhf  = (_Float16*)d_ws;
  _Float16* khf  = qhf  + (size_t)32768 * 256;
  _Float16* vthf = khf  + (size_t)32768 * 256;
  _Float16* whf  = vthf + (size_t)32768 * 256;   // ~48.4 MB total

  wconv_kernel<<<768, 256, 0, stream>>>(Wq, Wk, Wv, whf);
  proj_kernel<<<512, 256, 0, stream>>>(traj, bq, bk, bv, whf, qhf, khf, vthf);
  attn_kernel<<<dim3(16, 32), 256, 0, stream>>>(qhf, khf, vthf, (float*)d_out);
}

// Round 4
// 380.447 us; speedup vs baseline: 1.1974x; 1.1974x over previous
//
#include <hip/hip_runtime.h>

// B=32, N=1024, D=256. out = softmax((x Wq^T + bq)(x Wk^T + bk)^T) (x Wv^T + bv)
// fp16 MFMA, fp32 accumulate. R4: K/V/W pre-packed in MFMA-fragment-major layout
// (each fragment = contiguous 1KB chunk, lane-indexed) -> all B-operand loads are
// perfectly coalesced global loads; attn kt-loop has ZERO barriers.
#define NN 1024
#define DD 256

typedef __attribute__((ext_vector_type(8))) _Float16 f16x8;  // 8 fp16 = 4 VGPRs
typedef __attribute__((ext_vector_type(4))) float f32x4;

union H8 { f16x8 v; _Float16 s[8]; };

// ---------------- kernel 1: pack W fp32 -> fp16 fragment-major -----------------------
// pw chunk id c = ((et*8+kk)*4+nt)*64+lane ; data = W[e=et*64+nt*16+col16][d=kk*32+quad*8..+7]
__global__ void wconv_kernel(const float* __restrict__ Wq, const float* __restrict__ Wk,
                             const float* __restrict__ Wv, _Float16* __restrict__ pw) {
  int c = blockIdx.x * 256 + threadIdx.x;        // < 24576
  int lane = c & 63;
  int nt = (c >> 6) & 3;
  int kk = (c >> 8) & 7;
  int et = c >> 11;                              // 0..11
  int e = et * 64 + nt * 16 + (lane & 15);
  int d = kk * 32 + (lane >> 4) * 8;
  const float* W = (e < 256) ? Wq : (e < 512 ? Wk : Wv);
  const float* src = W + (e & 255) * 256 + d;
  H8 xx;
  for (int j = 0; j < 8; ++j) xx.s[j] = (_Float16)src[j];
  *(f16x8*)(pw + (size_t)c * 8) = xx.v;
}

// ---------------- kernel 2: QKV projection -------------------------------------------
// grid 512, 256 thr. Block = 64 m-rows x all 768 e-cols. W fragments direct from packed
// global (coalesced). Epilogue stores q row-major, k/v in packed fragment layout.
__global__ __launch_bounds__(256, 4) void proj_kernel(
    const float* __restrict__ traj,
    const float* __restrict__ bq, const float* __restrict__ bk, const float* __restrict__ bv,
    const _Float16* __restrict__ pw,
    _Float16* __restrict__ qhf, _Float16* __restrict__ pk, _Float16* __restrict__ pv)
{
  __shared__ _Float16 Cs[64 * 88];    // 11264 B epilogue staging

  const int t = threadIdx.x;
  const int lane = t & 63, wave = t >> 6;
  const int col16 = lane & 15, quad = lane >> 4;
  const int mbase = blockIdx.x * 64;

  // A fragments from global fp32 (A[m=lane&15][k=quad*8+j]); once per block.
  f16x8 aq[8];
  {
    const float* ap = traj + (size_t)(mbase + wave * 16 + col16) * DD;
    for (int kk = 0; kk < 8; ++kk) {
      float4 u0 = *(const float4*)(ap + kk * 32 + quad * 8);
      float4 u1 = *(const float4*)(ap + kk * 32 + quad * 8 + 4);
      H8 xx;
      xx.s[0] = (_Float16)u0.x; xx.s[1] = (_Float16)u0.y;
      xx.s[2] = (_Float16)u0.z; xx.s[3] = (_Float16)u0.w;
      xx.s[4] = (_Float16)u1.x; xx.s[5] = (_Float16)u1.y;
      xx.s[6] = (_Float16)u1.z; xx.s[7] = (_Float16)u1.w;
      aq[kk] = xx.v;
    }
  }

  const f32x4 zero = {0.f, 0.f, 0.f, 0.f};
  const int bb = mbase >> 10;

  for (int et = 0; et < 12; ++et) {
    f32x4 acc[4];
    acc[0] = zero; acc[1] = zero; acc[2] = zero; acc[3] = zero;
    const _Float16* wb = pw + (size_t)et * 8 * 4 * 64 * 8;
    for (int kk = 0; kk < 8; ++kk)
      for (int nt = 0; nt < 4; ++nt) {
        f16x8 bw = *(const f16x8*)(wb + (size_t)((kk * 4 + nt) * 64 + lane) * 8);
        acc[nt] = __builtin_amdgcn_mfma_f32_16x16x32_f16(aq[kk], bw, acc[nt], 0, 0, 0);
      }

    int ebase = et * 64;
    int sel = ebase >> 8;                    // 0=q 1=k 2=v
    const float* bias = (sel == 0) ? bq : (sel == 1 ? bk : bv);
    for (int nt = 0; nt < 4; ++nt) {
      float bvl = bias[(ebase & 255) + nt * 16 + col16];
      acc[nt][0] += bvl; acc[nt][1] += bvl; acc[nt][2] += bvl; acc[nt][3] += bvl;
    }
    __syncthreads();                         // prev iteration's Cs reads done
    if (sel == 0) {
      // q row-major: stage C layout (col=lane&15, row=quad*4+r), store 256-col rows
      for (int nt = 0; nt < 4; ++nt)
        for (int r = 0; r < 4; ++r)
          Cs[(wave * 16 + quad * 4 + r) * 88 + nt * 16 + col16] = (_Float16)acc[nt][r];
      __syncthreads();
      int row = t >> 2;
      int colg = ebase;
      for (int i = 0; i < 2; ++i) {
        int c = (t & 3) + i * 4;
        *(int4*)(qhf + (size_t)(mbase + row) * 256 + colg + c * 8) =
            *(const int4*)&Cs[row * 88 + c * 8];
      }
    } else if (sel == 1) {
      // k packed: pk[((bb*64+kg)*8+kkg)*64+lane_c] = K[key=kg*16+c16][d=kkg*32+qd*8..]
      for (int nt = 0; nt < 4; ++nt)
        for (int r = 0; r < 4; ++r)
          Cs[(wave * 16 + quad * 4 + r) * 88 + nt * 16 + col16] = (_Float16)acc[nt][r];
      __syncthreads();
      for (int i = 0; i < 2; ++i) {
        int cc = t + i * 256;
        int lane_c = cc & 63, kk2 = (cc >> 6) & 1, kg = cc >> 7;   // kg 0..3
        f16x8 val = *(const f16x8*)&Cs[(kg * 16 + (lane_c & 15)) * 88 +
                                       kk2 * 32 + (lane_c >> 4) * 8];
        int kgg = ((mbase & 1023) >> 4) + kg;
        int kkg = ((ebase - 256) >> 5) + kk2;
        *(f16x8*)(pk + (size_t)(((bb * 64 + kgg) * 8 + kkg) * 64 + lane_c) * 8) = val;
      }
    } else {
      // v packed: stage transposed [e_local][m_local], then
      // pv[(((bb*16+kt)*2+k2)*16+dtg)*64+lane_c] = V[key=k2*32+qd*8..][d=dtg*16+c16]
      for (int nt = 0; nt < 4; ++nt)
        for (int r = 0; r < 4; ++r)
          Cs[(nt * 16 + col16) * 88 + (wave * 16 + quad * 4 + r)] = (_Float16)acc[nt][r];
      __syncthreads();
      int kt = (mbase & 1023) >> 6;
      for (int i = 0; i < 2; ++i) {
        int cc = t + i * 256;
        int lane_c = cc & 63, k2 = (cc >> 6) & 1, dtl = cc >> 7;   // dtl 0..3
        f16x8 val = *(const f16x8*)&Cs[(dtl * 16 + (lane_c & 15)) * 88 +
                                       k2 * 32 + (lane_c >> 4) * 8];
        int dtg = ((ebase - 512) >> 4) + dtl;
        *(f16x8*)(pv + (size_t)((((bb * 16 + kt) * 2 + k2) * 16 + dtg) * 64 + lane_c) * 8) = val;
      }
    }
  }
}

// ---------------- kernel 3: flash attention ------------------------------------------
// grid (16,32): x = q-tile (64 rows), y = batch. 4 waves, wave owns 16 q-rows.
// K/V fragments direct from packed global (1KB coalesced loads); zero barriers.
__global__ __launch_bounds__(256, 3) void attn_kernel(
    const _Float16* __restrict__ qhf, const _Float16* __restrict__ pk,
    const _Float16* __restrict__ pv, float* __restrict__ out)
{
  __shared__ _Float16 Ps[64 * 88];     // 11264 B, wave-private 16-row regions

  const int t = threadIdx.x;
  const int lane = t & 63, wave = t >> 6;
  const int col16 = lane & 15, quad = lane >> 4;
  const int qt = blockIdx.x, b = blockIdx.y;
  const int qrow0 = b * NN + qt * 64;

  // Q fragments from global fp16 (once per kernel)
  f16x8 aq[8];
  {
    const _Float16* qp = qhf + (size_t)(qrow0 + wave * 16 + col16) * DD;
    for (int kk = 0; kk < 8; ++kk)
      aq[kk] = *(const f16x8*)(qp + kk * 32 + quad * 8);
  }

  float m_i[4], l_i[4], alpha[4];
  f32x4 O[16];
  const f32x4 zero = {0.f, 0.f, 0.f, 0.f};
  for (int r = 0; r < 4; ++r) { m_i[r] = -3.0e38f; l_i[r] = 0.f; }
  for (int dt = 0; dt < 16; ++dt) O[dt] = zero;

  const _Float16* kbb = pk + (size_t)b * 64 * 8 * 64 * 8;    // [kg][kk][lane]
  const _Float16* vbb = pv + (size_t)b * 16 * 2 * 16 * 64 * 8; // [kt][k2][dt][lane]

  for (int kt = 0; kt < 16; ++kt) {
    // S = Q K^T (64 keys); fragment (kg=kt*4+nt, kk) at contiguous 1KB chunks
    f32x4 S[4]; S[0] = zero; S[1] = zero; S[2] = zero; S[3] = zero;
    for (int kk = 0; kk < 8; ++kk)
      for (int nt = 0; nt < 4; ++nt) {
        f16x8 bk_ = *(const f16x8*)(kbb + (size_t)(((kt * 4 + nt) * 8 + kk) * 64 + lane) * 8);
        S[nt] = __builtin_amdgcn_mfma_f32_16x16x32_f16(aq[kk], bk_, S[nt], 0, 0, 0);
      }

    // online softmax — rows quad*4+r private to this wave's quads
    for (int r = 0; r < 4; ++r) {
      float vmax = fmaxf(fmaxf(S[0][r], S[1][r]), fmaxf(S[2][r], S[3][r]));
      vmax = fmaxf(vmax, __shfl_xor(vmax, 1));
      vmax = fmaxf(vmax, __shfl_xor(vmax, 2));
      vmax = fmaxf(vmax, __shfl_xor(vmax, 4));
      vmax = fmaxf(vmax, __shfl_xor(vmax, 8));
      float nm = fmaxf(m_i[r], vmax);
      alpha[r] = __expf(m_i[r] - nm);
      float rs = 0.f;
      for (int nt = 0; nt < 4; ++nt) {
        float pv_ = __expf(S[nt][r] - nm);
        S[nt][r] = pv_;
        rs += pv_;
      }
      rs += __shfl_xor(rs, 1);
      rs += __shfl_xor(rs, 2);
      rs += __shfl_xor(rs, 4);
      rs += __shfl_xor(rs, 8);
      l_i[r] = l_i[r] * alpha[r] + rs;
      m_i[r] = nm;
    }
    for (int dt = 0; dt < 16; ++dt)
      for (int r = 0; r < 4; ++r) O[dt][r] *= alpha[r];

    // P -> LDS (C layout -> A layout; wave-private rows, no barrier)
    for (int nt = 0; nt < 4; ++nt)
      for (int r = 0; r < 4; ++r)
        Ps[(wave * 16 + quad * 4 + r) * 88 + nt * 16 + col16] = (_Float16)S[nt][r];
    f16x8 ap[2];
    for (int k2 = 0; k2 < 2; ++k2)
      ap[k2] = *(const f16x8*)&Ps[(wave * 16 + col16) * 88 + k2 * 32 + quad * 8];

    // O += P V; fragment (kt,k2,dt) contiguous 1KB chunks
    const _Float16* vb = vbb + (size_t)kt * 2 * 16 * 64 * 8;
    for (int dt = 0; dt < 16; ++dt)
      for (int k2 = 0; k2 < 2; ++k2) {
        f16x8 bv_ = *(const f16x8*)(vb + (size_t)((k2 * 16 + dt) * 64 + lane) * 8);
        O[dt] = __builtin_amdgcn_mfma_f32_16x16x32_f16(ap[k2], bv_, O[dt], 0, 0, 0);
      }
  }

  // epilogue: O /= l, fp32 store
  for (int r = 0; r < 4; ++r) {
    float inv = 1.0f / l_i[r];
    float* orow = out + (size_t)(qrow0 + wave * 16 + quad * 4 + r) * DD;
    for (int dt = 0; dt < 16; ++dt)
      orow[dt * 16 + col16] = O[dt][r] * inv;
  }
}

// ---------------- launch -------------------------------------------------------------
extern "C" void kernel_launch(void* const* d_in, const int* in_sizes, int n_in,
                              void* d_out, int out_size, void* d_ws, size_t ws_size,
                              hipStream_t stream) {
  const float* traj = (const float*)d_in[0];
  const float* Wq   = (const float*)d_in[1];
  const float* bq   = (const float*)d_in[2];
  const float* Wk   = (const float*)d_in[3];
  const float* bk   = (const float*)d_in[4];
  const float* Wv   = (const float*)d_in[5];
  const float* bv   = (const float*)d_in[6];

  // workspace (fp16): q[32768][256] | pk packed 16MB | pv packed 16MB | pw packed 0.4MB
  _Float16* qhf = (_Float16*)d_ws;
  _Float16* pk  = qhf + (size_t)32768 * 256;
  _Float16* pv  = pk  + (size_t)32768 * 256;
  _Float16* pw  = pv  + (size_t)32768 * 256;   // ~48.4 MB total

  wconv_kernel<<<96, 256, 0, stream>>>(Wq, Wk, Wv, pw);
  proj_kernel<<<512, 256, 0, stream>>>(traj, bq, bk, bv, pw, qhf, pk, pv);
  attn_kernel<<<dim3(16, 32), 256, 0, stream>>>(qhf, pk, pv, (float*)d_out);
}

// Round 5
// 207.064 us; speedup vs baseline: 2.2001x; 1.8373x over previous
//
#include <hip/hip_runtime.h>

// B=32, N=1024, D=256. out = softmax((x Wq^T + bq)(x Wk^T + bk)^T) (x Wv^T + bv)
// fp16 MFMA, fp32 accumulate. R5: packed fragment-major global layouts (R4) +
// async global_load_lds staging (m97 pattern). Staging is a linear 16B/lane copy;
// all LDS reads are lane-linear ds_read_b128 (conflict-free). 37.9/44 KB LDS ->
// 3 blocks/CU in both hot kernels.
#define NN 1024
#define DD 256

typedef __attribute__((ext_vector_type(8))) _Float16 f16x8;  // 8 fp16 = 4 VGPRs
typedef __attribute__((ext_vector_type(4))) float f32x4;

union H8 { f16x8 v; _Float16 s[8]; };

__device__ __forceinline__ void g2lds16(const void* g, void* l) {
  __builtin_amdgcn_global_load_lds(
      (const __attribute__((address_space(1))) void*)g,
      (__attribute__((address_space(3))) void*)l, 16, 0, 0);
}

// ---------------- kernel 1: pack W fp32 -> fp16 fragment-major -----------------------
// pw chunk c = ((et*8+kk)*4+nt)*64+lane ; data = W[e=et*64+nt*16+col16][d=kk*32+quad*8..+7]
__global__ void wconv_kernel(const float* __restrict__ Wq, const float* __restrict__ Wk,
                             const float* __restrict__ Wv, _Float16* __restrict__ pw) {
  int c = blockIdx.x * 256 + threadIdx.x;        // < 24576
  int lane = c & 63;
  int nt = (c >> 6) & 3;
  int kk = (c >> 8) & 7;
  int et = c >> 11;                              // 0..11
  int e = et * 64 + nt * 16 + (lane & 15);
  int d = kk * 32 + (lane >> 4) * 8;
  const float* W = (e < 256) ? Wq : (e < 512 ? Wk : Wv);
  const float* src = W + (e & 255) * 256 + d;
  H8 xx;
  for (int j = 0; j < 8; ++j) xx.s[j] = (_Float16)src[j];
  *(f16x8*)(pw + (size_t)c * 8) = xx.v;
}

// ---------------- kernel 2: QKV projection -------------------------------------------
// grid 512, 256 thr, 64 m-rows x all 768 e-cols. W tile (32KB) staged via
// global_load_lds each et. Outputs all in packed fragment-major layout.
__global__ __launch_bounds__(256, 3) void proj_kernel(
    const float* __restrict__ traj,
    const float* __restrict__ bq, const float* __restrict__ bk, const float* __restrict__ bv,
    const _Float16* __restrict__ pw,
    _Float16* __restrict__ pq, _Float16* __restrict__ pk, _Float16* __restrict__ pv)
{
  __shared__ _Float16 Wl[16384];      // 32 KB: one 64-col W tile, fragment-major
  __shared__ _Float16 Cs[64 * 88];    // 11264 B epilogue staging -> 44 KB total

  const int t = threadIdx.x;
  const int lane = t & 63, wave = t >> 6;
  const int col16 = lane & 15, quad = lane >> 4;
  const int mbase = blockIdx.x * 64;

  // A fragments from global fp32 (A[m=lane&15][k=quad*8+j]); once per block.
  f16x8 aq[8];
  {
    const float* ap = traj + (size_t)(mbase + wave * 16 + col16) * DD;
    for (int kk = 0; kk < 8; ++kk) {
      float4 u0 = *(const float4*)(ap + kk * 32 + quad * 8);
      float4 u1 = *(const float4*)(ap + kk * 32 + quad * 8 + 4);
      H8 xx;
      xx.s[0] = (_Float16)u0.x; xx.s[1] = (_Float16)u0.y;
      xx.s[2] = (_Float16)u0.z; xx.s[3] = (_Float16)u0.w;
      xx.s[4] = (_Float16)u1.x; xx.s[5] = (_Float16)u1.y;
      xx.s[6] = (_Float16)u1.z; xx.s[7] = (_Float16)u1.w;
      aq[kk] = xx.v;
    }
  }

  const f32x4 zero = {0.f, 0.f, 0.f, 0.f};
  const int bb = mbase >> 10;

  for (int et = 0; et < 12; ++et) {
    __syncthreads();                         // Wl free (prev reads done) + Cs free
    {                                        // stage 32 KB W tile, linear 16B/thread
      const _Float16* ws = pw + (size_t)et * 16384;
      for (int i = 0; i < 8; ++i)
        g2lds16(ws + (size_t)(i * 256 + t) * 8, Wl + (i * 256 + t) * 8);
    }
    __syncthreads();                         // staged data visible

    f32x4 acc[4];
    acc[0] = zero; acc[1] = zero; acc[2] = zero; acc[3] = zero;
    for (int kk = 0; kk < 8; ++kk)
      for (int nt = 0; nt < 4; ++nt) {
        f16x8 bw = *(const f16x8*)&Wl[((kk * 4 + nt) * 64 + lane) * 8];
        acc[nt] = __builtin_amdgcn_mfma_f32_16x16x32_f16(aq[kk], bw, acc[nt], 0, 0, 0);
      }

    int ebase = et * 64;
    int sel = ebase >> 8;                    // 0=q 1=k 2=v
    const float* bias = (sel == 0) ? bq : (sel == 1 ? bk : bv);
    for (int nt = 0; nt < 4; ++nt) {
      float bvl = bias[(ebase & 255) + nt * 16 + col16];
      acc[nt][0] += bvl; acc[nt][1] += bvl; acc[nt][2] += bvl; acc[nt][3] += bvl;
    }
    if (sel < 2) {
      // stage C layout (col=lane&15, row=quad*4+r)
      for (int nt = 0; nt < 4; ++nt)
        for (int r = 0; r < 4; ++r)
          Cs[(wave * 16 + quad * 4 + r) * 88 + nt * 16 + col16] = (_Float16)acc[nt][r];
      __syncthreads();
      if (sel == 0) {
        // q packed: pq[(g*8+kk)*64+lane], g = 16-row group, A-frag layout
        int g = (mbase >> 4) + wave;
        for (int kkloc = 0; kkloc < 2; ++kkloc) {
          f16x8 val = *(const f16x8*)&Cs[(wave * 16 + col16) * 88 + kkloc * 32 + quad * 8];
          *(f16x8*)(pq + (size_t)((g * 8 + et * 2 + kkloc) * 64 + lane) * 8) = val;
        }
      } else {
        // k packed: pk[((bb*64+kg)*8+kkg)*64+lane_c] = K[key=kg*16+c16][d=kkg*32+qd*8..]
        for (int i = 0; i < 2; ++i) {
          int cc = t + i * 256;
          int lane_c = cc & 63, kk2 = (cc >> 6) & 1, kg = cc >> 7;   // kg 0..3
          f16x8 val = *(const f16x8*)&Cs[(kg * 16 + (lane_c & 15)) * 88 +
                                         kk2 * 32 + (lane_c >> 4) * 8];
          int kgg = ((mbase & 1023) >> 4) + kg;
          int kkg = ((ebase - 256) >> 5) + kk2;
          *(f16x8*)(pk + (size_t)(((bb * 64 + kgg) * 8 + kkg) * 64 + lane_c) * 8) = val;
        }
      }
    } else {
      // v packed: stage transposed [e_local][m_local], then
      // pv[((bb*32+kt32)*16+dtg)*64+lane_c] = V[key=(kt32%2)*32+qd*8..][d=dtg*16+c16]
      for (int nt = 0; nt < 4; ++nt)
        for (int r = 0; r < 4; ++r)
          Cs[(nt * 16 + col16) * 88 + (wave * 16 + quad * 4 + r)] = (_Float16)acc[nt][r];
      __syncthreads();
      int kt64 = (mbase & 1023) >> 6;
      for (int i = 0; i < 2; ++i) {
        int cc = t + i * 256;
        int lane_c = cc & 63, k2 = (cc >> 6) & 1, dtl = cc >> 7;   // dtl 0..3
        f16x8 val = *(const f16x8*)&Cs[(dtl * 16 + (lane_c & 15)) * 88 +
                                       k2 * 32 + (lane_c >> 4) * 8];
        int dtg = ((ebase - 512) >> 4) + dtl;
        int kt32 = kt64 * 2 + k2;
        *(f16x8*)(pv + (size_t)(((bb * 32 + kt32) * 16 + dtg) * 64 + lane_c) * 8) = val;
      }
    }
  }
}

// ---------------- kernel 3: flash attention ------------------------------------------
// grid (16,32): x = q-tile (64 rows), y = batch. 4 waves, wave owns 16 q-rows.
// 32-key tiles staged via global_load_lds (16KB K + 16KB V); LDS 37.9KB -> 3 blk/CU.
__global__ __launch_bounds__(256, 3) void attn_kernel(
    const _Float16* __restrict__ pq, const _Float16* __restrict__ pk,
    const _Float16* __restrict__ pv, float* __restrict__ out)
{
  __shared__ _Float16 Ks[8192];       // 16 KB: 32 keys x 256 d, fragment-major
  __shared__ _Float16 Vs[8192];       // 16 KB: 32 keys x 256 d
  __shared__ _Float16 Ps[64 * 40];    // 5120 B, wave-private 16-row regions

  const int t = threadIdx.x;
  const int lane = t & 63, wave = t >> 6;
  const int col16 = lane & 15, quad = lane >> 4;
  const int qt = blockIdx.x, b = blockIdx.y;
  const int qrow0 = b * NN + qt * 64;

  // Q fragments from packed global (lane-linear, once per kernel)
  f16x8 aq[8];
  {
    int g = b * 64 + qt * 4 + wave;
    for (int kk = 0; kk < 8; ++kk)
      aq[kk] = *(const f16x8*)(pq + (size_t)((g * 8 + kk) * 64 + lane) * 8);
  }

  float m_i[4], l_i[4], alpha[4];
  f32x4 O[16];
  const f32x4 zero = {0.f, 0.f, 0.f, 0.f};
  for (int r = 0; r < 4; ++r) { m_i[r] = -3.0e38f; l_i[r] = 0.f; }
  for (int dt = 0; dt < 16; ++dt) O[dt] = zero;

  const _Float16* kbb = pk + (size_t)b * 64 * 8 * 64 * 8;   // per-batch K (16 MB/32)
  const _Float16* vbb = pv + (size_t)b * 32 * 16 * 64 * 8;  // per-batch V

  for (int kt = 0; kt < 32; ++kt) {
    __syncthreads();                         // prev tile's LDS reads done
    {                                        // stage K+V tile: 32 KB, linear 16B/thread
      const _Float16* kg = kbb + (size_t)kt * 8192;
      const _Float16* vg = vbb + (size_t)kt * 8192;
      for (int i = 0; i < 4; ++i)
        g2lds16(kg + (size_t)(i * 256 + t) * 8, Ks + (i * 256 + t) * 8);
      for (int i = 0; i < 4; ++i)
        g2lds16(vg + (size_t)(i * 256 + t) * 8, Vs + (i * 256 + t) * 8);
    }
    __syncthreads();                         // staged data visible

    // S = Q K^T (32 keys)
    f32x4 S[2]; S[0] = zero; S[1] = zero;
    for (int kk = 0; kk < 8; ++kk)
      for (int nt = 0; nt < 2; ++nt) {
        f16x8 bk_ = *(const f16x8*)&Ks[((nt * 8 + kk) * 64 + lane) * 8];
        S[nt] = __builtin_amdgcn_mfma_f32_16x16x32_f16(aq[kk], bk_, S[nt], 0, 0, 0);
      }

    // online softmax — rows quad*4+r private to this wave's quads
    for (int r = 0; r < 4; ++r) {
      float vmax = fmaxf(S[0][r], S[1][r]);
      vmax = fmaxf(vmax, __shfl_xor(vmax, 1));
      vmax = fmaxf(vmax, __shfl_xor(vmax, 2));
      vmax = fmaxf(vmax, __shfl_xor(vmax, 4));
      vmax = fmaxf(vmax, __shfl_xor(vmax, 8));
      float nm = fmaxf(m_i[r], vmax);
      alpha[r] = __expf(m_i[r] - nm);
      float p0 = __expf(S[0][r] - nm);
      float p1 = __expf(S[1][r] - nm);
      S[0][r] = p0; S[1][r] = p1;
      float rs = p0 + p1;
      rs += __shfl_xor(rs, 1);
      rs += __shfl_xor(rs, 2);
      rs += __shfl_xor(rs, 4);
      rs += __shfl_xor(rs, 8);
      l_i[r] = l_i[r] * alpha[r] + rs;
      m_i[r] = nm;
    }
    for (int dt = 0; dt < 16; ++dt)
      for (int r = 0; r < 4; ++r) O[dt][r] *= alpha[r];

    // P -> LDS (C layout -> A layout; wave-private rows, no barrier)
    for (int nt = 0; nt < 2; ++nt)
      for (int r = 0; r < 4; ++r)
        Ps[(wave * 16 + quad * 4 + r) * 40 + nt * 16 + col16] = (_Float16)S[nt][r];
    f16x8 ap = *(const f16x8*)&Ps[(wave * 16 + col16) * 40 + quad * 8];

    // O += P V (one 32-k step per dt)
    for (int dt = 0; dt < 16; ++dt) {
      f16x8 bv_ = *(const f16x8*)&Vs[(dt * 64 + lane) * 8];
      O[dt] = __builtin_amdgcn_mfma_f32_16x16x32_f16(ap, bv_, O[dt], 0, 0, 0);
    }
  }

  // epilogue: O /= l, fp32 store
  for (int r = 0; r < 4; ++r) {
    float inv = 1.0f / l_i[r];
    float* orow = out + (size_t)(qrow0 + wave * 16 + quad * 4 + r) * DD;
    for (int dt = 0; dt < 16; ++dt)
      orow[dt * 16 + col16] = O[dt][r] * inv;
  }
}

// ---------------- launch -------------------------------------------------------------
extern "C" void kernel_launch(void* const* d_in, const int* in_sizes, int n_in,
                              void* d_out, int out_size, void* d_ws, size_t ws_size,
                              hipStream_t stream) {
  const float* traj = (const float*)d_in[0];
  const float* Wq   = (const float*)d_in[1];
  const float* bq   = (const float*)d_in[2];
  const float* Wk   = (const float*)d_in[3];
  const float* bk   = (const float*)d_in[4];
  const float* Wv   = (const float*)d_in[5];
  const float* bv   = (const float*)d_in[6];

  // workspace (fp16): pq 16MB | pk 16MB | pv 16MB | pw 0.4MB  (all packed fragment-major)
  _Float16* pq = (_Float16*)d_ws;
  _Float16* pk = pq + (size_t)32768 * 256;
  _Float16* pv = pk + (size_t)32768 * 256;
  _Float16* pw = pv + (size_t)32768 * 256;   // ~48.4 MB total

  wconv_kernel<<<96, 256, 0, stream>>>(Wq, Wk, Wv, pw);
  proj_kernel<<<512, 256, 0, stream>>>(traj, bq, bk, bv, pw, pq, pk, pv);
  attn_kernel<<<dim3(16, 32), 256, 0, stream>>>(pq, pk, pv, (float*)d_out);
}